// Round 5
// baseline (651.347 us; speedup 1.0000x reference)
//
#include <hip/hip_runtime.h>
#include <hip/hip_fp16.h>
#include <math.h>

// H = 64 features, N = 50000 nodes, E = 1.6M edges.
// d_out = [ new_mean (N*64) | new_std (N*64) | total_kl (1) ]
//
// Pipeline:
//   1. counting-sort edges by dst into CSR (esrc + fp16 weight arrays)
//   2. pack mean/var rows into one fp16 array, 256 B/node (fused into hist)
//   3. aggregate: wave/node, 4 edge-groups x 16 lanes, lane16 = chunk id;
//      8 edges in flight/group-iter; __hfma2 packed accumulate with f32 flush
//      every 8 edges; then in-wave 64x64 transform (aggregation commutes with
//      the linear map), fused bias + sqrt(exp(x)+1e-6).
//
// ws: counts/cursor [NP] | offsets [NP+16] | partials [256]
//     | esrc int[E] | ewh ushort[E] | pk uint[n*64] (16B-aligned)

#define NBLK_SCAN 196            // 196*256 = 50176 >= 50000
#define NP (NBLK_SCAN * 256)

// hist (edge dst counts) + pack (fp16 feature table), fused.
__global__ __launch_bounds__(256) void k_hist_pack(const int* __restrict__ ei,
                                                   int* __restrict__ counts, int E,
                                                   const float* __restrict__ mean,
                                                   const float* __restrict__ stdv,
                                                   uint* __restrict__ pk, int total) {
    int tid = blockIdx.x * 256 + threadIdx.x;
    if (tid < E) atomicAdd(&counts[ei[E + tid]], 1);
    if (tid < total) {
        int node = tid >> 6, q = tid & 63;
        int c = q >> 2, j = q & 3;
        int t = c & 1, o = c >> 1;
        int f0 = 8 * o + 2 * j;
        const float* src = t ? stdv : mean;
        float2 v = *reinterpret_cast<const float2*>(src + (size_t)node * 64 + f0);
        float a = v.x, b = v.y;
        if (t) { a = a * a; b = b * b; }
        __half2 h2 = __floats2half2_rn(a, b);
        pk[tid] = *reinterpret_cast<uint*>(&h2);
    }
}

__global__ __launch_bounds__(256) void k_scan_block(const int* __restrict__ counts,
                                                    int* __restrict__ offsets,
                                                    int* __restrict__ partials) {
    __shared__ int s[256];
    int i = blockIdx.x * 256 + threadIdx.x;
    int v = counts[i];
    s[threadIdx.x] = v;
    __syncthreads();
    for (int off = 1; off < 256; off <<= 1) {
        int t = 0;
        if (threadIdx.x >= off) t = s[threadIdx.x - off];
        __syncthreads();
        s[threadIdx.x] += t;
        __syncthreads();
    }
    offsets[i] = s[threadIdx.x] - v;           // exclusive
    if (threadIdx.x == 255) partials[blockIdx.x] = s[255];
}

// block 0: exclusive scan of partials; block 1: KL reduction.
__global__ __launch_bounds__(256) void k_scan_part_kl(int* __restrict__ partials,
                                                      const float* __restrict__ Wm_mu,
                                                      const float* __restrict__ Wm_ls,
                                                      const float* __restrict__ Ws_mu,
                                                      const float* __restrict__ Ws_ls,
                                                      float* __restrict__ okl) {
    if (blockIdx.x == 0) {
        __shared__ int s[256];
        int v = (threadIdx.x < NBLK_SCAN) ? partials[threadIdx.x] : 0;
        s[threadIdx.x] = v;
        __syncthreads();
        for (int off = 1; off < 256; off <<= 1) {
            int t = 0;
            if (threadIdx.x >= off) t = s[threadIdx.x - off];
            __syncthreads();
            s[threadIdx.x] += t;
            __syncthreads();
        }
        partials[threadIdx.x] = s[threadIdx.x] - v;  // exclusive
    } else {
        __shared__ float red[256];
        const float C = -2.3025850929940457f - 0.5f;  // log(0.1) - 0.5
        float acc = 0.f;
        for (int i = threadIdx.x; i < 4096; i += 256) {
            {
                float mu = Wm_mu[i], ls = Wm_ls[i];
                float s = expf(ls);
                acc += C - ls + (s * s + mu * mu) * 50.0f;  // 1/(2*0.1^2)
            }
            {
                float mu = Ws_mu[i], ls = Ws_ls[i];
                float s = expf(ls);
                acc += C - ls + (s * s + mu * mu) * 50.0f;
            }
        }
        red[threadIdx.x] = acc;
        __syncthreads();
        for (int s = 128; s > 0; s >>= 1) {
            if (threadIdx.x < s) red[threadIdx.x] += red[threadIdx.x + s];
            __syncthreads();
        }
        if (threadIdx.x == 0) okl[0] = red[0];
    }
}

__global__ __launch_bounds__(256) void k_scan_add(int* __restrict__ offsets,
                                                  const int* __restrict__ partials,
                                                  int* __restrict__ cursor) {
    int i = blockIdx.x * 256 + threadIdx.x;
    int o = offsets[i] + partials[blockIdx.x];
    offsets[i] = o;
    cursor[i] = o;
}

__global__ __launch_bounds__(256) void k_scatter_edges(const int* __restrict__ ei,
                                                       const float* __restrict__ ew,
                                                       int* __restrict__ cursor,
                                                       int* __restrict__ esrc,
                                                       ushort* __restrict__ ewh, int E) {
    int t = blockIdx.x * 256 + threadIdx.x;
    if (t >= E) return;
    int src = ei[t];
    int dst = ei[E + t];
    float w = ew[t];
    int pos = atomicAdd(&cursor[dst], 1);
    esrc[pos] = src;
    ewh[pos] = __half_as_ushort(__float2half(w));   // RNE
}

// One wave per node (grid-strided, 1280 blocks x 4 waves, 5 blocks/CU).
// __launch_bounds__(256,5): 5 waves/EU -> VGPR capped at ~102 -> 20 waves/CU.
__global__ __launch_bounds__(256, 5) void k_aggregate(const uint* __restrict__ pk,
                                                      const int* __restrict__ offsets,
                                                      const int* __restrict__ esrc,
                                                      const ushort* __restrict__ ewh,
                                                      const float* __restrict__ Wm,
                                                      const float* __restrict__ Ws,
                                                      const float* __restrict__ bm,
                                                      const float* __restrict__ bs,
                                                      float* __restrict__ om,
                                                      float* __restrict__ os, int n) {
    __shared__ float sWm[64][64];
    __shared__ float sWs[64][64];
    for (int i = threadIdx.x; i < 4096; i += 256) {
        sWm[i >> 6][i & 63] = Wm[i];
        sWs[i >> 6][i & 63] = Ws[i];
    }
    __syncthreads();

    const int lane = threadIdx.x & 63;
    const int wid  = threadIdx.x >> 6;
    const int g    = lane >> 4;      // edge subgroup 0..3
    const int l16  = lane & 15;      // chunk id: t = l16&1 (0=mean,1=var)
    const int t    = l16 & 1;
    const float bmv = bm[lane];
    const float bsv = bs[lane];

    for (int node = blockIdx.x * 4 + wid; node < n; node += gridDim.x * 4) {
        const int start = offsets[node];
        const int cnt   = offsets[node + 1] - start;

        float accf[8] = {0.f, 0.f, 0.f, 0.f, 0.f, 0.f, 0.f, 0.f};

        for (int base = 0; base < cnt; base += 64) {
            int m = cnt - base;
            if (m > 64) m = 64;
            int es = 0, wb = 0;                    // fp16 0x0000 == 0.0f
            if (lane < m) {
                es = esrc[start + base + lane];
                wb = ewh[start + base + lane];
            }
            int mr = (m + 31) & ~31;               // 32 or 64

            for (int j0 = 0; j0 < mr; j0 += 32) {
                int     srcs[8];
                __half2 wh[8];
#pragma unroll
                for (int u = 0; u < 8; ++u) {
                    int j = j0 + 4 * u + g;
                    srcs[u] = __shfl(es, j, 64);
                    int w16 = __shfl(wb, j, 64);
                    float w = __half2float(__ushort_as_half((ushort)w16));
                    float wl = t ? w * w : w;
                    __half h = __float2half(wl);
                    wh[u] = __halves2half2(h, h);
                }
                uint4 dd[8];
#pragma unroll
                for (int u = 0; u < 8; ++u)
                    dd[u] = *reinterpret_cast<const uint4*>(
                        pk + (size_t)srcs[u] * 64 + l16 * 4);

                __half2 a0 = __halves2half2(__half(0.f), __half(0.f));
                __half2 a1 = a0, a2 = a0, a3 = a0;
#pragma unroll
                for (int u = 0; u < 8; ++u) {
                    a0 = __hfma2(*reinterpret_cast<__half2*>(&dd[u].x), wh[u], a0);
                    a1 = __hfma2(*reinterpret_cast<__half2*>(&dd[u].y), wh[u], a1);
                    a2 = __hfma2(*reinterpret_cast<__half2*>(&dd[u].z), wh[u], a2);
                    a3 = __hfma2(*reinterpret_cast<__half2*>(&dd[u].w), wh[u], a3);
                }
                // flush to f32 (error window = 8 edges)
                float2 f;
                f = __half22float2(a0); accf[0] += f.x; accf[1] += f.y;
                f = __half22float2(a1); accf[2] += f.x; accf[3] += f.y;
                f = __half22float2(a2); accf[4] += f.x; accf[5] += f.y;
                f = __half22float2(a3); accf[6] += f.x; accf[7] += f.y;
            }
        }

        // Reduce across the 4 edge-groups (bits 4,5 of lane).
#pragma unroll
        for (int c = 0; c < 8; ++c) {
            accf[c] += __shfl_xor(accf[c], 16, 64);
            accf[c] += __shfl_xor(accf[c], 32, 64);
        }
        // Lane l16 holds accf[c] = aggregated feature 8*(l16>>1)+c of type l16&1.

        float am = 0.f, as_ = 0.f;
#pragma unroll
        for (int k = 0; k < 64; ++k) {
            float a = __shfl(accf[k & 7], (k >> 3) * 2, 64);       // mean lane
            float b = __shfl(accf[k & 7], (k >> 3) * 2 + 1, 64);   // var lane
            am  += a * sWm[k][lane];
            as_ += b * sWs[k][lane];
        }
        om[(size_t)node * 64 + lane] = am + bmv;
        float lv = as_ + bsv;
        os[(size_t)node * 64 + lane] = sqrtf(expf(lv) + 1e-6f);
    }
}

extern "C" void kernel_launch(void* const* d_in, const int* in_sizes, int n_in,
                              void* d_out, int out_size, void* d_ws, size_t ws_size,
                              hipStream_t stream) {
    const float* mean  = (const float*)d_in[0];
    const float* stdv  = (const float*)d_in[1];
    const int*   ei    = (const int*)d_in[2];
    const float* ew    = (const float*)d_in[3];
    const float* Wm_mu = (const float*)d_in[4];
    const float* Wm_ls = (const float*)d_in[5];
    const float* bm    = (const float*)d_in[6];
    const float* Ws_mu = (const float*)d_in[7];
    const float* Ws_ls = (const float*)d_in[8];
    const float* bs    = (const float*)d_in[9];

    const int n = in_sizes[0] / 64;   // 50000
    const int E = in_sizes[3];        // 1600000
    const int total = n * 64;

    float* om  = (float*)d_out;
    float* os  = om + total;
    float* okl = om + 2 * total;

    char* wsb = (char*)d_ws;
    int* counts   = (int*)wsb;                 // doubles as cursor after scan
    int* offsets  = counts + NP;
    int* partials = offsets + NP + 16;
    int* esrc     = partials + 256;
    ushort* ewh   = (ushort*)(esrc + E);
    size_t pk_off = ((size_t)((char*)(ewh + E) - wsb) + 15) & ~(size_t)15;
    uint* pk      = (uint*)(wsb + pk_off);

    hipMemsetAsync(counts, 0, NP * sizeof(int), stream);
    int hp_blocks = (total > E ? total : E);
    hp_blocks = (hp_blocks + 255) / 256;
    k_hist_pack<<<hp_blocks, 256, 0, stream>>>(ei, counts, E, mean, stdv, pk, total);
    k_scan_block<<<NBLK_SCAN, 256, 0, stream>>>(counts, offsets, partials);
    k_scan_part_kl<<<2, 256, 0, stream>>>(partials, Wm_mu, Wm_ls, Ws_mu, Ws_ls, okl);
    k_scan_add<<<NBLK_SCAN, 256, 0, stream>>>(offsets, partials, counts);
    k_scatter_edges<<<(E + 255) / 256, 256, 0, stream>>>(ei, ew, counts, esrc, ewh, E);
    k_aggregate<<<1280, 256, 0, stream>>>(pk, offsets, esrc, ewh,
                                          Wm_mu, Ws_mu, bm, bs, om, os, n);
}

// Round 6
// 391.012 us; speedup vs baseline: 1.6658x; 1.6658x over previous
//
#include <hip/hip_runtime.h>
#include <hip/hip_fp16.h>
#include <math.h>

// H = 64, N = 50000 nodes, E = 1.6M edges.
// d_out = [ new_mean (N*64) | new_std (N*64) | total_kl (1) ]
//
// Pipeline (transform BEFORE aggregation; both are linear so they commute):
//   1. counting-sort edges by dst into CSR of packed records (w16<<16|src)
//   2. k_transform: h_m = mean@Wm, h_v = (std^2)@Ws, written as packed fp16,
//      256 B/node: chunk c (=lane16 of consumer): t=c&1 (0=mean,1=var),
//      o=c>>1; uint j holds features 8o+2j, 8o+2j+1.
//   3. k_aggregate: one wave per node, 4 edge-groups x 16 lanes, 8 edges in
//      flight per group-iter, __hfma2 accumulate + f32 flush every 8 edges,
//      fused bias + sqrt(exp(x)+1e-6) epilogue. No LDS, no in-wave GEMM.
//
// ws: counts/cursor [NP] | offsets [NP+16] | partials [256]
//     | erec uint[E] | pk uint[n*64] (16B-aligned)   (~20.8 MB)

#define NBLK_SCAN 196            // 196*256 = 50176 >= 50000
#define NP (NBLK_SCAN * 256)

__global__ __launch_bounds__(256) void k_hist(const int* __restrict__ ei,
                                              int* __restrict__ counts, int E) {
    int t = blockIdx.x * 256 + threadIdx.x;
    if (t < E) atomicAdd(&counts[ei[E + t]], 1);
}

__global__ __launch_bounds__(256) void k_scan_block(const int* __restrict__ counts,
                                                    int* __restrict__ offsets,
                                                    int* __restrict__ partials) {
    __shared__ int s[256];
    int i = blockIdx.x * 256 + threadIdx.x;
    int v = counts[i];
    s[threadIdx.x] = v;
    __syncthreads();
    for (int off = 1; off < 256; off <<= 1) {
        int t = 0;
        if (threadIdx.x >= off) t = s[threadIdx.x - off];
        __syncthreads();
        s[threadIdx.x] += t;
        __syncthreads();
    }
    offsets[i] = s[threadIdx.x] - v;           // exclusive
    if (threadIdx.x == 255) partials[blockIdx.x] = s[255];
}

// block 0: exclusive scan of partials; block 1: KL reduction.
__global__ __launch_bounds__(256) void k_scan_part_kl(int* __restrict__ partials,
                                                      const float* __restrict__ Wm_mu,
                                                      const float* __restrict__ Wm_ls,
                                                      const float* __restrict__ Ws_mu,
                                                      const float* __restrict__ Ws_ls,
                                                      float* __restrict__ okl) {
    if (blockIdx.x == 0) {
        __shared__ int s[256];
        int v = (threadIdx.x < NBLK_SCAN) ? partials[threadIdx.x] : 0;
        s[threadIdx.x] = v;
        __syncthreads();
        for (int off = 1; off < 256; off <<= 1) {
            int t = 0;
            if (threadIdx.x >= off) t = s[threadIdx.x - off];
            __syncthreads();
            s[threadIdx.x] += t;
            __syncthreads();
        }
        partials[threadIdx.x] = s[threadIdx.x] - v;  // exclusive
    } else {
        __shared__ float red[256];
        const float C = -2.3025850929940457f - 0.5f;  // log(0.1) - 0.5
        float acc = 0.f;
        for (int i = threadIdx.x; i < 4096; i += 256) {
            {
                float mu = Wm_mu[i], ls = Wm_ls[i];
                float s = expf(ls);
                acc += C - ls + (s * s + mu * mu) * 50.0f;  // 1/(2*0.1^2)
            }
            {
                float mu = Ws_mu[i], ls = Ws_ls[i];
                float s = expf(ls);
                acc += C - ls + (s * s + mu * mu) * 50.0f;
            }
        }
        red[threadIdx.x] = acc;
        __syncthreads();
        for (int s = 128; s > 0; s >>= 1) {
            if (threadIdx.x < s) red[threadIdx.x] += red[threadIdx.x + s];
            __syncthreads();
        }
        if (threadIdx.x == 0) okl[0] = red[0];
    }
}

__global__ __launch_bounds__(256) void k_scan_add(int* __restrict__ offsets,
                                                  const int* __restrict__ partials,
                                                  int* __restrict__ cursor) {
    int i = blockIdx.x * 256 + threadIdx.x;
    int o = offsets[i] + partials[blockIdx.x];
    offsets[i] = o;
    cursor[i] = o;
}

// One packed record per edge: (fp16(w) << 16) | src   (src < 65536).
__global__ __launch_bounds__(256) void k_scatter_edges(const int* __restrict__ ei,
                                                       const float* __restrict__ ew,
                                                       int* __restrict__ cursor,
                                                       uint* __restrict__ erec, int E) {
    int t = blockIdx.x * 256 + threadIdx.x;
    if (t >= E) return;
    int src = ei[t];
    int dst = ei[E + t];
    float w = ew[t];
    uint w16 = (uint)__half_as_ushort(__float2half(w));   // RNE
    int pos = atomicAdd(&cursor[dst], 1);
    erec[pos] = (w16 << 16) | (uint)src;
}

// Dense transform + fp16 pack: h_m = mean@Wm, h_v = (std^2)@Ws.
// 64 rows per block (4 waves x 16 rows), shfl-broadcast GEMM, W in LDS.
__global__ __launch_bounds__(256) void k_transform(const float* __restrict__ mean,
                                                   const float* __restrict__ stdv,
                                                   const float* __restrict__ Wm,
                                                   const float* __restrict__ Ws,
                                                   uint* __restrict__ pk, int n) {
    __shared__ float sWm[64][64];
    __shared__ float sWs[64][64];
    for (int i = threadIdx.x; i < 4096; i += 256) {
        sWm[i >> 6][i & 63] = Wm[i];
        sWs[i >> 6][i & 63] = Ws[i];
    }
    __syncthreads();
    const int lane = threadIdx.x & 63;      // = input feature k and output f
    const int wid  = threadIdx.x >> 6;
    const int base = blockIdx.x * 64;
    for (int r = wid; r < 64; r += 4) {
        int node = base + r;
        if (node >= n) return;
        float mv = mean[(size_t)node * 64 + lane];
        float sv = stdv[(size_t)node * 64 + lane];
        float vv = sv * sv;
        float am = 0.f, av = 0.f;
#pragma unroll
        for (int k = 0; k < 64; ++k) {
            float a = __shfl(mv, k, 64);
            float b = __shfl(vv, k, 64);
            am += a * sWm[k][lane];
            av += b * sWs[k][lane];
        }
        float am1 = __shfl(am, lane + 1, 64);
        float av1 = __shfl(av, lane + 1, 64);
        if (!(lane & 1)) {
            int f = lane, o = f >> 3, j = (f >> 1) & 3;
            size_t bidx = (size_t)node * 64 + 8 * o + j;
            __half2 hm = __floats2half2_rn(am, am1);
            __half2 hv = __floats2half2_rn(av, av1);
            pk[bidx]     = *reinterpret_cast<uint*>(&hm);   // t=0 chunk
            pk[bidx + 4] = *reinterpret_cast<uint*>(&hv);   // t=1 chunk
        }
    }
}

// One wave per node. Wave = 4 edge-groups x 16 lanes; lane16 = chunk id.
__global__ __launch_bounds__(256) void k_aggregate(const uint* __restrict__ pk,
                                                   const int* __restrict__ offsets,
                                                   const uint* __restrict__ erec,
                                                   const float* __restrict__ bm,
                                                   const float* __restrict__ bs,
                                                   float* __restrict__ om,
                                                   float* __restrict__ os, int n) {
    const int lane = threadIdx.x & 63;
    const int wid  = threadIdx.x >> 6;
    const int g    = lane >> 4;      // edge subgroup 0..3
    const int l16  = lane & 15;      // chunk id: t=l16&1, o=l16>>1
    const int t    = l16 & 1;

    const int node = blockIdx.x * 4 + wid;
    if (node >= n) return;
    const int start = offsets[node];
    const int cnt   = offsets[node + 1] - start;

    float accf[8] = {0.f, 0.f, 0.f, 0.f, 0.f, 0.f, 0.f, 0.f};

    for (int base = 0; base < cnt; base += 64) {
        int m = cnt - base;
        if (m > 64) m = 64;
        uint rec = 0;                          // w16=0 -> w=0.0f
        if (lane < m) rec = erec[start + base + lane];
        int mr = (m + 31) & ~31;               // 32 or 64

        for (int j0 = 0; j0 < mr; j0 += 32) {
            uint rr[8];
#pragma unroll
            for (int u = 0; u < 8; ++u)
                rr[u] = (uint)__shfl((int)rec, j0 + 4 * u + g, 64);
            uint4 dd[8];
#pragma unroll
            for (int u = 0; u < 8; ++u)
                dd[u] = *reinterpret_cast<const uint4*>(
                    pk + (size_t)(rr[u] & 0xFFFFu) * 64 + l16 * 4);
            __half2 wh[8];
#pragma unroll
            for (int u = 0; u < 8; ++u) {
                float w = __half2float(__ushort_as_half((ushort)(rr[u] >> 16)));
                float wl = t ? w * w : w;
                __half h = __float2half(wl);
                wh[u] = __halves2half2(h, h);
            }
            __half2 a0 = __halves2half2(__half(0.f), __half(0.f));
            __half2 a1 = a0, a2 = a0, a3 = a0;
#pragma unroll
            for (int u = 0; u < 8; ++u) {
                a0 = __hfma2(*reinterpret_cast<__half2*>(&dd[u].x), wh[u], a0);
                a1 = __hfma2(*reinterpret_cast<__half2*>(&dd[u].y), wh[u], a1);
                a2 = __hfma2(*reinterpret_cast<__half2*>(&dd[u].z), wh[u], a2);
                a3 = __hfma2(*reinterpret_cast<__half2*>(&dd[u].w), wh[u], a3);
            }
            float2 f;
            f = __half22float2(a0); accf[0] += f.x; accf[1] += f.y;
            f = __half22float2(a1); accf[2] += f.x; accf[3] += f.y;
            f = __half22float2(a2); accf[4] += f.x; accf[5] += f.y;
            f = __half22float2(a3); accf[6] += f.x; accf[7] += f.y;
        }
    }

    // Reduce across the 4 edge-groups (bits 4,5 of lane); result replicated.
#pragma unroll
    for (int c = 0; c < 8; ++c) {
        accf[c] += __shfl_xor(accf[c], 16, 64);
        accf[c] += __shfl_xor(accf[c], 32, 64);
    }
    // Lane l16 holds accf[c] = aggregated feature 8*(l16>>1)+c of type l16&1.

    if (g == 0) {
        const int f0 = (l16 >> 1) * 8;
        if (!t) {
            float4 b0 = *reinterpret_cast<const float4*>(bm + f0);
            float4 b1 = *reinterpret_cast<const float4*>(bm + f0 + 4);
            float4 r0 = {accf[0] + b0.x, accf[1] + b0.y, accf[2] + b0.z, accf[3] + b0.w};
            float4 r1 = {accf[4] + b1.x, accf[5] + b1.y, accf[6] + b1.z, accf[7] + b1.w};
            *reinterpret_cast<float4*>(om + (size_t)node * 64 + f0)     = r0;
            *reinterpret_cast<float4*>(om + (size_t)node * 64 + f0 + 4) = r1;
        } else {
            float4 b0 = *reinterpret_cast<const float4*>(bs + f0);
            float4 b1 = *reinterpret_cast<const float4*>(bs + f0 + 4);
            float4 r0, r1;
            r0.x = sqrtf(expf(accf[0] + b0.x) + 1e-6f);
            r0.y = sqrtf(expf(accf[1] + b0.y) + 1e-6f);
            r0.z = sqrtf(expf(accf[2] + b0.z) + 1e-6f);
            r0.w = sqrtf(expf(accf[3] + b0.w) + 1e-6f);
            r1.x = sqrtf(expf(accf[4] + b1.x) + 1e-6f);
            r1.y = sqrtf(expf(accf[5] + b1.y) + 1e-6f);
            r1.z = sqrtf(expf(accf[6] + b1.z) + 1e-6f);
            r1.w = sqrtf(expf(accf[7] + b1.w) + 1e-6f);
            *reinterpret_cast<float4*>(os + (size_t)node * 64 + f0)     = r0;
            *reinterpret_cast<float4*>(os + (size_t)node * 64 + f0 + 4) = r1;
        }
    }
}

extern "C" void kernel_launch(void* const* d_in, const int* in_sizes, int n_in,
                              void* d_out, int out_size, void* d_ws, size_t ws_size,
                              hipStream_t stream) {
    const float* mean  = (const float*)d_in[0];
    const float* stdv  = (const float*)d_in[1];
    const int*   ei    = (const int*)d_in[2];
    const float* ew    = (const float*)d_in[3];
    const float* Wm_mu = (const float*)d_in[4];
    const float* Wm_ls = (const float*)d_in[5];
    const float* bm    = (const float*)d_in[6];
    const float* Ws_mu = (const float*)d_in[7];
    const float* Ws_ls = (const float*)d_in[8];
    const float* bs    = (const float*)d_in[9];

    const int n = in_sizes[0] / 64;   // 50000
    const int E = in_sizes[3];        // 1600000
    const int total = n * 64;

    float* om  = (float*)d_out;
    float* os  = om + total;
    float* okl = om + 2 * total;

    char* wsb = (char*)d_ws;
    int* counts   = (int*)wsb;                 // doubles as cursor after scan
    int* offsets  = counts + NP;
    int* partials = offsets + NP + 16;
    uint* erec    = (uint*)(partials + 256);
    size_t pk_off = ((size_t)((char*)(erec + E) - wsb) + 15) & ~(size_t)15;
    uint* pk      = (uint*)(wsb + pk_off);     // ~20.8 MB total

    hipMemsetAsync(counts, 0, NP * sizeof(int), stream);
    k_hist<<<(E + 255) / 256, 256, 0, stream>>>(ei, counts, E);
    k_scan_block<<<NBLK_SCAN, 256, 0, stream>>>(counts, offsets, partials);
    k_scan_part_kl<<<2, 256, 0, stream>>>(partials, Wm_mu, Wm_ls, Ws_mu, Ws_ls, okl);
    k_scan_add<<<NBLK_SCAN, 256, 0, stream>>>(offsets, partials, counts);
    k_scatter_edges<<<(E + 255) / 256, 256, 0, stream>>>(ei, ew, counts, erec, E);
    k_transform<<<(n + 63) / 64, 256, 0, stream>>>(mean, stdv, Wm_mu, Ws_mu, pk, n);
    k_aggregate<<<(n + 3) / 4, 256, 0, stream>>>(pk, offsets, erec, bm, bs, om, os, n);
}

// Round 7
// 280.632 us; speedup vs baseline: 2.3210x; 1.3933x over previous
//
#include <hip/hip_runtime.h>
#include <hip/hip_fp16.h>
#include <math.h>

// H = 64, N = 50000 nodes, E = 1.6M edges.
// d_out = [ new_mean (N*64) | new_std (N*64) | total_kl (1) ]
//
// Pipeline (transform BEFORE aggregation; both linear, they commute):
//   1. counting-sort edges by dst into CSR of packed records (w16<<16|src)
//   2. k_transform (MFMA 16x16x32_f16): h_m = mean@Wm, h_v = (std^2)@Ws,
//      written as packed fp16 table pk, 256 B/node:
//      uint q = c*4+j, c: t=c&1 (0=mean,1=var), o=c>>1; holds feats 8o+2j, 8o+2j+1.
//   3. k_aggregate: one wave per node, 4 edge-groups x 16 lanes, 8 edges in
//      flight per group-iter, __hfma2 accumulate + f32 flush, fused
//      bias + sqrt(exp(x)+1e-6) epilogue. No LDS, no in-wave GEMM.
//
// ws: counts/cursor [NP] | offsets [NP+16] | partials [256]
//     | erec uint[E] | pk uint[n*64] (16B-aligned)

#define NBLK_SCAN 196            // 196*256 = 50176 >= 50000
#define NP (NBLK_SCAN * 256)

typedef _Float16 half8 __attribute__((ext_vector_type(8)));
typedef float f32x4 __attribute__((ext_vector_type(4)));

__global__ __launch_bounds__(256) void k_hist(const int* __restrict__ ei,
                                              int* __restrict__ counts, int E) {
    int t = blockIdx.x * 256 + threadIdx.x;
    if (t < E) atomicAdd(&counts[ei[E + t]], 1);
}

__global__ __launch_bounds__(256) void k_scan_block(const int* __restrict__ counts,
                                                    int* __restrict__ offsets,
                                                    int* __restrict__ partials) {
    __shared__ int s[256];
    int i = blockIdx.x * 256 + threadIdx.x;
    int v = counts[i];
    s[threadIdx.x] = v;
    __syncthreads();
    for (int off = 1; off < 256; off <<= 1) {
        int t = 0;
        if (threadIdx.x >= off) t = s[threadIdx.x - off];
        __syncthreads();
        s[threadIdx.x] += t;
        __syncthreads();
    }
    offsets[i] = s[threadIdx.x] - v;           // exclusive
    if (threadIdx.x == 255) partials[blockIdx.x] = s[255];
}

// block 0: exclusive scan of partials; block 1: KL reduction.
__global__ __launch_bounds__(256) void k_scan_part_kl(int* __restrict__ partials,
                                                      const float* __restrict__ Wm_mu,
                                                      const float* __restrict__ Wm_ls,
                                                      const float* __restrict__ Ws_mu,
                                                      const float* __restrict__ Ws_ls,
                                                      float* __restrict__ okl) {
    if (blockIdx.x == 0) {
        __shared__ int s[256];
        int v = (threadIdx.x < NBLK_SCAN) ? partials[threadIdx.x] : 0;
        s[threadIdx.x] = v;
        __syncthreads();
        for (int off = 1; off < 256; off <<= 1) {
            int t = 0;
            if (threadIdx.x >= off) t = s[threadIdx.x - off];
            __syncthreads();
            s[threadIdx.x] += t;
            __syncthreads();
        }
        partials[threadIdx.x] = s[threadIdx.x] - v;  // exclusive
    } else {
        __shared__ float red[256];
        const float C = -2.3025850929940457f - 0.5f;  // log(0.1) - 0.5
        float acc = 0.f;
        for (int i = threadIdx.x; i < 4096; i += 256) {
            {
                float mu = Wm_mu[i], ls = Wm_ls[i];
                float s = expf(ls);
                acc += C - ls + (s * s + mu * mu) * 50.0f;  // 1/(2*0.1^2)
            }
            {
                float mu = Ws_mu[i], ls = Ws_ls[i];
                float s = expf(ls);
                acc += C - ls + (s * s + mu * mu) * 50.0f;
            }
        }
        red[threadIdx.x] = acc;
        __syncthreads();
        for (int s = 128; s > 0; s >>= 1) {
            if (threadIdx.x < s) red[threadIdx.x] += red[threadIdx.x + s];
            __syncthreads();
        }
        if (threadIdx.x == 0) okl[0] = red[0];
    }
}

__global__ __launch_bounds__(256) void k_scan_add(int* __restrict__ offsets,
                                                  const int* __restrict__ partials,
                                                  int* __restrict__ cursor) {
    int i = blockIdx.x * 256 + threadIdx.x;
    int o = offsets[i] + partials[blockIdx.x];
    offsets[i] = o;
    cursor[i] = o;
}

// One packed record per edge: (fp16(w) << 16) | src   (src < 65536).
__global__ __launch_bounds__(256) void k_scatter_edges(const int* __restrict__ ei,
                                                       const float* __restrict__ ew,
                                                       int* __restrict__ cursor,
                                                       uint* __restrict__ erec, int E) {
    int t = blockIdx.x * 256 + threadIdx.x;
    if (t >= E) return;
    int src = ei[t];
    int dst = ei[E + t];
    float w = ew[t];
    uint w16 = (uint)__half_as_ushort(__float2half(w));   // RNE
    int pos = atomicAdd(&cursor[dst], 1);
    erec[pos] = (w16 << 16) | (uint)src;
}

// MFMA transform: h_m = mean@Wm, h_v = (std^2)@Ws, packed fp16 out.
// Block = 4 waves x 16 nodes = 64 nodes. Per wave: 4 col-tiles x 2 K-halves
// x 2 matrices = 16 x mfma_f32_16x16x32_f16.
// Fragment convention (consistent kappa for A and B, so any k-permutation
// cancels): A[row=l&15][k=32*kk+8*(l>>4)+j], B[k same][col=l&15].
// C/D (HW-verified): col=lane&15, row=(lane>>4)*4+reg.
__global__ __launch_bounds__(256) void k_transform(const float* __restrict__ mean,
                                                   const float* __restrict__ stdv,
                                                   const float* __restrict__ Wm,
                                                   const float* __restrict__ Ws,
                                                   uint* __restrict__ pk, int n) {
    __shared__ float sW[2 * 4096];
    for (int i = threadIdx.x; i < 4096; i += 256) {
        sW[i] = Wm[i];
        sW[4096 + i] = Ws[i];
    }
    __syncthreads();

    const int lane = threadIdx.x & 63;
    const int wid  = threadIdx.x >> 6;
    const int l16  = lane & 15;
    const int lg   = lane >> 4;          // 0..3

    // B fragments, register-resident: bw[t][kk][c]
    half8 bw[2][2][4];
#pragma unroll
    for (int t = 0; t < 2; ++t)
#pragma unroll
        for (int kk = 0; kk < 2; ++kk)
#pragma unroll
            for (int c = 0; c < 4; ++c) {
                half8 h;
#pragma unroll
                for (int j = 0; j < 8; ++j)
                    h[j] = (_Float16)sW[t * 4096 + (32 * kk + 8 * lg + j) * 64 + 16 * c + l16];
                bw[t][kk][c] = h;
            }

    const int nb = blockIdx.x * 64 + wid * 16;
    int arow = nb + l16;
    if (arow >= n) arow = n - 1;         // clamp; rows >= n never stored

    half8 am[2], av[2];
#pragma unroll
    for (int kk = 0; kk < 2; ++kk) {
        const float* mp = mean + (size_t)arow * 64 + 32 * kk + 8 * lg;
        const float* sp = stdv + (size_t)arow * 64 + 32 * kk + 8 * lg;
        float4 m0 = *(const float4*)mp;
        float4 m1 = *(const float4*)(mp + 4);
        float4 s0 = *(const float4*)sp;
        float4 s1 = *(const float4*)(sp + 4);
        half8 a, v;
        a[0] = (_Float16)m0.x; a[1] = (_Float16)m0.y;
        a[2] = (_Float16)m0.z; a[3] = (_Float16)m0.w;
        a[4] = (_Float16)m1.x; a[5] = (_Float16)m1.y;
        a[6] = (_Float16)m1.z; a[7] = (_Float16)m1.w;
        v[0] = (_Float16)(s0.x * s0.x); v[1] = (_Float16)(s0.y * s0.y);
        v[2] = (_Float16)(s0.z * s0.z); v[3] = (_Float16)(s0.w * s0.w);
        v[4] = (_Float16)(s1.x * s1.x); v[5] = (_Float16)(s1.y * s1.y);
        v[6] = (_Float16)(s1.z * s1.z); v[7] = (_Float16)(s1.w * s1.w);
        am[kk] = a; av[kk] = v;
    }

    f32x4 accm[4], accs[4];
    const f32x4 z = {0.f, 0.f, 0.f, 0.f};
#pragma unroll
    for (int c = 0; c < 4; ++c) { accm[c] = z; accs[c] = z; }

#pragma unroll
    for (int c = 0; c < 4; ++c) {
        accm[c] = __builtin_amdgcn_mfma_f32_16x16x32_f16(am[0], bw[0][0][c], accm[c], 0, 0, 0);
        accm[c] = __builtin_amdgcn_mfma_f32_16x16x32_f16(am[1], bw[0][1][c], accm[c], 0, 0, 0);
        accs[c] = __builtin_amdgcn_mfma_f32_16x16x32_f16(av[0], bw[1][0][c], accs[c], 0, 0, 0);
        accs[c] = __builtin_amdgcn_mfma_f32_16x16x32_f16(av[1], bw[1][1][c], accs[c], 0, 0, 0);
    }

    // Pack+store. Lane holds (node = nb+4*lg+r, F = 16c+l16). Feature pairs
    // (F, F+1) live in adjacent lanes -> shfl_xor(1).
#pragma unroll
    for (int c = 0; c < 4; ++c) {
        const int F = 16 * c + l16;
#pragma unroll
        for (int r = 0; r < 4; ++r) {
            int node = nb + 4 * lg + r;
            float mv = accm[c][r];
            float vv = accs[c][r];
            float mp = __shfl_xor(mv, 1, 64);
            float vp = __shfl_xor(vv, 1, 64);
            if (!(l16 & 1) && node < n) {
                int o = F >> 3, j = (F & 7) >> 1;
                __half2 hm = __floats2half2_rn(mv, mp);
                __half2 hv = __floats2half2_rn(vv, vp);
                pk[(size_t)node * 64 + 8 * o + j]     = *reinterpret_cast<uint*>(&hm);
                pk[(size_t)node * 64 + 8 * o + 4 + j] = *reinterpret_cast<uint*>(&hv);
            }
        }
    }
}

// One wave per node. Wave = 4 edge-groups x 16 lanes; lane16 = chunk id.
__global__ __launch_bounds__(256) void k_aggregate(const uint* __restrict__ pk,
                                                   const int* __restrict__ offsets,
                                                   const uint* __restrict__ erec,
                                                   const float* __restrict__ bm,
                                                   const float* __restrict__ bs,
                                                   float* __restrict__ om,
                                                   float* __restrict__ os, int n) {
    const int lane = threadIdx.x & 63;
    const int wid  = threadIdx.x >> 6;
    const int g    = lane >> 4;      // edge subgroup 0..3
    const int l16  = lane & 15;      // chunk id: t=l16&1, o=l16>>1
    const int t    = l16 & 1;

    const int node = blockIdx.x * 4 + wid;
    if (node >= n) return;
    const int start = offsets[node];
    const int cnt   = offsets[node + 1] - start;

    float accf[8] = {0.f, 0.f, 0.f, 0.f, 0.f, 0.f, 0.f, 0.f};

    for (int base = 0; base < cnt; base += 64) {
        int m = cnt - base;
        if (m > 64) m = 64;
        uint rec = 0;                          // w16=0 -> w=0.0f
        if (lane < m) rec = erec[start + base + lane];
        int mr = (m + 31) & ~31;               // 32 or 64

        for (int j0 = 0; j0 < mr; j0 += 32) {
            uint rr[8];
#pragma unroll
            for (int u = 0; u < 8; ++u)
                rr[u] = (uint)__shfl((int)rec, j0 + 4 * u + g, 64);
            uint4 dd[8];
#pragma unroll
            for (int u = 0; u < 8; ++u)
                dd[u] = *reinterpret_cast<const uint4*>(
                    pk + (size_t)(rr[u] & 0xFFFFu) * 64 + l16 * 4);
            __half2 wh[8];
#pragma unroll
            for (int u = 0; u < 8; ++u) {
                float w = __half2float(__ushort_as_half((ushort)(rr[u] >> 16)));
                float wl = t ? w * w : w;
                __half h = __float2half(wl);
                wh[u] = __halves2half2(h, h);
            }
            __half2 a0 = __halves2half2(__half(0.f), __half(0.f));
            __half2 a1 = a0, a2 = a0, a3 = a0;
#pragma unroll
            for (int u = 0; u < 8; ++u) {
                a0 = __hfma2(*reinterpret_cast<__half2*>(&dd[u].x), wh[u], a0);
                a1 = __hfma2(*reinterpret_cast<__half2*>(&dd[u].y), wh[u], a1);
                a2 = __hfma2(*reinterpret_cast<__half2*>(&dd[u].z), wh[u], a2);
                a3 = __hfma2(*reinterpret_cast<__half2*>(&dd[u].w), wh[u], a3);
            }
            float2 f;
            f = __half22float2(a0); accf[0] += f.x; accf[1] += f.y;
            f = __half22float2(a1); accf[2] += f.x; accf[3] += f.y;
            f = __half22float2(a2); accf[4] += f.x; accf[5] += f.y;
            f = __half22float2(a3); accf[6] += f.x; accf[7] += f.y;
        }
    }

    // Reduce across the 4 edge-groups (bits 4,5 of lane); result replicated.
#pragma unroll
    for (int c = 0; c < 8; ++c) {
        accf[c] += __shfl_xor(accf[c], 16, 64);
        accf[c] += __shfl_xor(accf[c], 32, 64);
    }
    // Lane l16 holds accf[c] = aggregated feature 8*(l16>>1)+c of type l16&1.

    if (g == 0) {
        const int f0 = (l16 >> 1) * 8;
        if (!t) {
            float4 b0 = *reinterpret_cast<const float4*>(bm + f0);
            float4 b1 = *reinterpret_cast<const float4*>(bm + f0 + 4);
            float4 r0 = {accf[0] + b0.x, accf[1] + b0.y, accf[2] + b0.z, accf[3] + b0.w};
            float4 r1 = {accf[4] + b1.x, accf[5] + b1.y, accf[6] + b1.z, accf[7] + b1.w};
            *reinterpret_cast<float4*>(om + (size_t)node * 64 + f0)     = r0;
            *reinterpret_cast<float4*>(om + (size_t)node * 64 + f0 + 4) = r1;
        } else {
            float4 b0 = *reinterpret_cast<const float4*>(bs + f0);
            float4 b1 = *reinterpret_cast<const float4*>(bs + f0 + 4);
            float4 r0, r1;
            r0.x = sqrtf(expf(accf[0] + b0.x) + 1e-6f);
            r0.y = sqrtf(expf(accf[1] + b0.y) + 1e-6f);
            r0.z = sqrtf(expf(accf[2] + b0.z) + 1e-6f);
            r0.w = sqrtf(expf(accf[3] + b0.w) + 1e-6f);
            r1.x = sqrtf(expf(accf[4] + b1.x) + 1e-6f);
            r1.y = sqrtf(expf(accf[5] + b1.y) + 1e-6f);
            r1.z = sqrtf(expf(accf[6] + b1.z) + 1e-6f);
            r1.w = sqrtf(expf(accf[7] + b1.w) + 1e-6f);
            *reinterpret_cast<float4*>(os + (size_t)node * 64 + f0)     = r0;
            *reinterpret_cast<float4*>(os + (size_t)node * 64 + f0 + 4) = r1;
        }
    }
}

extern "C" void kernel_launch(void* const* d_in, const int* in_sizes, int n_in,
                              void* d_out, int out_size, void* d_ws, size_t ws_size,
                              hipStream_t stream) {
    const float* mean  = (const float*)d_in[0];
    const float* stdv  = (const float*)d_in[1];
    const int*   ei    = (const int*)d_in[2];
    const float* ew    = (const float*)d_in[3];
    const float* Wm_mu = (const float*)d_in[4];
    const float* Wm_ls = (const float*)d_in[5];
    const float* bm    = (const float*)d_in[6];
    const float* Ws_mu = (const float*)d_in[7];
    const float* Ws_ls = (const float*)d_in[8];
    const float* bs    = (const float*)d_in[9];

    const int n = in_sizes[0] / 64;   // 50000
    const int E = in_sizes[3];        // 1600000
    const int total = n * 64;

    float* om  = (float*)d_out;
    float* os  = om + total;
    float* okl = om + 2 * total;

    char* wsb = (char*)d_ws;
    int* counts   = (int*)wsb;                 // doubles as cursor after scan
    int* offsets  = counts + NP;
    int* partials = offsets + NP + 16;
    uint* erec    = (uint*)(partials + 256);
    size_t pk_off = ((size_t)((char*)(erec + E) - wsb) + 15) & ~(size_t)15;
    uint* pk      = (uint*)(wsb + pk_off);

    hipMemsetAsync(counts, 0, NP * sizeof(int), stream);
    k_hist<<<(E + 255) / 256, 256, 0, stream>>>(ei, counts, E);
    k_scan_block<<<NBLK_SCAN, 256, 0, stream>>>(counts, offsets, partials);
    k_scan_part_kl<<<2, 256, 0, stream>>>(partials, Wm_mu, Wm_ls, Ws_mu, Ws_ls, okl);
    k_scan_add<<<NBLK_SCAN, 256, 0, stream>>>(offsets, partials, counts);
    k_scatter_edges<<<(E + 255) / 256, 256, 0, stream>>>(ei, ew, counts, erec, E);
    k_transform<<<(n + 63) / 64, 256, 0, stream>>>(mean, stdv, Wm_mu, Ws_mu, pk, n);
    k_aggregate<<<(n + 3) / 4, 256, 0, stream>>>(pk, offsets, erec, bm, bs, om, os, n);
}

// Round 8
// 180.373 us; speedup vs baseline: 3.6111x; 1.5558x over previous
//
#include <hip/hip_runtime.h>
#include <hip/hip_fp16.h>
#include <math.h>

// H = 64, N = 50000 nodes, E = 1.6M edges.
// d_out = [ new_mean (N*64) | new_std (N*64) | total_kl (1) ]
//
// Pipeline (transform BEFORE aggregation; both linear, they commute):
//   1. k_bucket_hist: 196-bucket histogram of dst>>8 (LDS-staged)
//   2. k_bucket_scan_kl: scan bucket counts (block 0) + KL reduction (block 1)
//   3. k_bucket_scatter: group edges by bucket; per-block LDS ranking, one
//      cursor atomic per bucket per block, dense chunked writes
//   4. k_local_sort: one block per bucket; per-node count/scan/rank in LDS,
//      in-place permute of the bucket's contiguous record range; writes
//      final CSR offsets
//   5. k_transform (MFMA 16x16x32_f16): h_m = mean@Wm, h_v = (std^2)@Ws,
//      packed fp16 table pk (256 B/node)
//   6. k_aggregate: one wave per node, 4 edge-groups x 16 lanes, 8 edges
//      in flight, __hfma2 + f32 flush, fused bias + sqrt(exp(x)+1e-6)
//
// ws: bcnt[256] | bbase[288] | bcur[256] | offsets[NPAD+16]
//     | dlo uchar[E] | esrcw uint[E] | pk uint[n*64]   (~21 MB)

#define NB   196                 // buckets (dst >> 8), 256 nodes each
#define NPAD (NB * 256)          // 50176
#define MAXB 10240               // max edges/bucket (mean 8192, sigma ~90)

typedef _Float16 half8 __attribute__((ext_vector_type(8)));
typedef float f32x4 __attribute__((ext_vector_type(4)));

__global__ __launch_bounds__(256) void k_bucket_hist(const int* __restrict__ ei,
                                                     int* __restrict__ bcnt, int E) {
    __shared__ int l[NB];
    for (int i = threadIdx.x; i < NB; i += 256) l[i] = 0;
    __syncthreads();
    for (int t = blockIdx.x * 256 + threadIdx.x; t < E; t += gridDim.x * 256)
        atomicAdd(&l[ei[E + t] >> 8], 1);
    __syncthreads();
    for (int i = threadIdx.x; i < NB; i += 256)
        if (l[i]) atomicAdd(&bcnt[i], l[i]);
}

// block 0: exclusive scan of bucket counts -> bbase (+ total at [256]), bcur.
// block 1: KL reduction.
__global__ __launch_bounds__(256) void k_bucket_scan_kl(const int* __restrict__ bcnt,
                                                        int* __restrict__ bbase,
                                                        int* __restrict__ bcur,
                                                        const float* __restrict__ Wm_mu,
                                                        const float* __restrict__ Wm_ls,
                                                        const float* __restrict__ Ws_mu,
                                                        const float* __restrict__ Ws_ls,
                                                        float* __restrict__ okl) {
    if (blockIdx.x == 0) {
        __shared__ int s[256];
        int v = (threadIdx.x < NB) ? bcnt[threadIdx.x] : 0;
        s[threadIdx.x] = v;
        __syncthreads();
        for (int off = 1; off < 256; off <<= 1) {
            int t = 0;
            if (threadIdx.x >= off) t = s[threadIdx.x - off];
            __syncthreads();
            s[threadIdx.x] += t;
            __syncthreads();
        }
        int excl = s[threadIdx.x] - v;
        bbase[threadIdx.x] = excl;
        bcur[threadIdx.x] = excl;
        if (threadIdx.x == 255) bbase[256] = s[255];   // == E
    } else {
        __shared__ float red[256];
        const float C = -2.3025850929940457f - 0.5f;   // log(0.1) - 0.5
        float acc = 0.f;
        for (int i = threadIdx.x; i < 4096; i += 256) {
            {
                float mu = Wm_mu[i], ls = Wm_ls[i];
                float s = expf(ls);
                acc += C - ls + (s * s + mu * mu) * 50.0f;  // 1/(2*0.1^2)
            }
            {
                float mu = Ws_mu[i], ls = Ws_ls[i];
                float s = expf(ls);
                acc += C - ls + (s * s + mu * mu) * 50.0f;
            }
        }
        red[threadIdx.x] = acc;
        __syncthreads();
        for (int s = 128; s > 0; s >>= 1) {
            if (threadIdx.x < s) red[threadIdx.x] += red[threadIdx.x + s];
            __syncthreads();
        }
        if (threadIdx.x == 0) okl[0] = red[0];
    }
}

// Group edges into bucket regions. 1024 edges per block; per-block LDS
// ranking; one cursor atomic per (block, non-empty bucket); chunked writes.
__global__ __launch_bounds__(256) void k_bucket_scatter(const int* __restrict__ ei,
                                                        const float* __restrict__ ew,
                                                        int* __restrict__ bcur,
                                                        uint* __restrict__ esrcw,
                                                        uchar* __restrict__ dlo, int E) {
    __shared__ int lcnt[NB], lpos[NB];
    for (int i = threadIdx.x; i < NB; i += 256) lcnt[i] = 0;
    __syncthreads();
    const int base = blockIdx.x * 1024;
    uint sv[4]; int bb[4], rr[4]; uchar dl4[4]; bool ok[4];
#pragma unroll
    for (int u = 0; u < 4; ++u) {
        int gi = base + u * 256 + threadIdx.x;
        ok[u] = gi < E;
        if (ok[u]) {
            int src = ei[gi];
            int dst = ei[E + gi];
            float w = ew[gi];
            uint w16 = (uint)__half_as_ushort(__float2half(w));
            sv[u] = (w16 << 16) | (uint)src;
            bb[u] = dst >> 8;
            dl4[u] = (uchar)(dst & 255);
            rr[u] = atomicAdd(&lcnt[bb[u]], 1);
        }
    }
    __syncthreads();
    for (int i = threadIdx.x; i < NB; i += 256)
        lpos[i] = lcnt[i] ? atomicAdd(&bcur[i], lcnt[i]) : 0;
    __syncthreads();
#pragma unroll
    for (int u = 0; u < 4; ++u)
        if (ok[u]) {
            int gpos = lpos[bb[u]] + rr[u];
            esrcw[gpos] = sv[u];
            dlo[gpos] = dl4[u];
        }
}

// One block per bucket: per-node counting sort of the bucket's contiguous
// record range, in place (all reads staged in LDS before writes).
__global__ __launch_bounds__(256) void k_local_sort(const int* __restrict__ bbase,
                                                    uint* __restrict__ esrcw,
                                                    const uchar* __restrict__ dlo,
                                                    int* __restrict__ offsets) {
    __shared__ int ncnt[256], noff[256], s[256];
    __shared__ uint val[MAXB];
    __shared__ ushort rk[MAXB];
    __shared__ uchar dl[MAXB];
    const int b = blockIdx.x;
    const int base = bbase[b];
    int cnt = bbase[b + 1] - base;
    if (cnt > MAXB) cnt = MAXB;   // impossible for this input (22 sigma)
    ncnt[threadIdx.x] = 0;
    __syncthreads();
    for (int i = threadIdx.x; i < cnt; i += 256) {
        uchar d = dlo[base + i];
        dl[i] = d;
        rk[i] = (ushort)atomicAdd(&ncnt[d], 1);
        val[i] = esrcw[base + i];
    }
    __syncthreads();
    int v = ncnt[threadIdx.x];
    s[threadIdx.x] = v;
    __syncthreads();
    for (int off = 1; off < 256; off <<= 1) {
        int t = 0;
        if (threadIdx.x >= off) t = s[threadIdx.x - off];
        __syncthreads();
        s[threadIdx.x] += t;
        __syncthreads();
    }
    noff[threadIdx.x] = s[threadIdx.x] - v;
    offsets[b * 256 + threadIdx.x] = base + s[threadIdx.x] - v;
    __syncthreads();
    for (int i = threadIdx.x; i < cnt; i += 256)
        esrcw[base + noff[dl[i]] + rk[i]] = val[i];
}

// MFMA transform: h_m = mean@Wm, h_v = (std^2)@Ws, packed fp16 out.
// Block = 4 waves x 16 nodes = 64 nodes. Per wave: 4 col-tiles x 2 K-halves
// x 2 matrices = 16 x mfma_f32_16x16x32_f16.
// A[row=l&15][k=32*kk+8*(l>>4)+j], B[k same][col=l&15] (consistent kappa
// cancels); C/D (HW-verified): col=lane&15, row=(lane>>4)*4+reg.
__global__ __launch_bounds__(256) void k_transform(const float* __restrict__ mean,
                                                   const float* __restrict__ stdv,
                                                   const float* __restrict__ Wm,
                                                   const float* __restrict__ Ws,
                                                   uint* __restrict__ pk, int n) {
    __shared__ float sW[2 * 4096];
    for (int i = threadIdx.x; i < 4096; i += 256) {
        sW[i] = Wm[i];
        sW[4096 + i] = Ws[i];
    }
    __syncthreads();

    const int lane = threadIdx.x & 63;
    const int wid  = threadIdx.x >> 6;
    const int l16  = lane & 15;
    const int lg   = lane >> 4;          // 0..3

    half8 bw[2][2][4];
#pragma unroll
    for (int t = 0; t < 2; ++t)
#pragma unroll
        for (int kk = 0; kk < 2; ++kk)
#pragma unroll
            for (int c = 0; c < 4; ++c) {
                half8 h;
#pragma unroll
                for (int j = 0; j < 8; ++j)
                    h[j] = (_Float16)sW[t * 4096 + (32 * kk + 8 * lg + j) * 64 + 16 * c + l16];
                bw[t][kk][c] = h;
            }

    const int nb = blockIdx.x * 64 + wid * 16;
    int arow = nb + l16;
    if (arow >= n) arow = n - 1;         // clamp; rows >= n never stored

    half8 am[2], av[2];
#pragma unroll
    for (int kk = 0; kk < 2; ++kk) {
        const float* mp = mean + (size_t)arow * 64 + 32 * kk + 8 * lg;
        const float* sp = stdv + (size_t)arow * 64 + 32 * kk + 8 * lg;
        float4 m0 = *(const float4*)mp;
        float4 m1 = *(const float4*)(mp + 4);
        float4 s0 = *(const float4*)sp;
        float4 s1 = *(const float4*)(sp + 4);
        half8 a, v;
        a[0] = (_Float16)m0.x; a[1] = (_Float16)m0.y;
        a[2] = (_Float16)m0.z; a[3] = (_Float16)m0.w;
        a[4] = (_Float16)m1.x; a[5] = (_Float16)m1.y;
        a[6] = (_Float16)m1.z; a[7] = (_Float16)m1.w;
        v[0] = (_Float16)(s0.x * s0.x); v[1] = (_Float16)(s0.y * s0.y);
        v[2] = (_Float16)(s0.z * s0.z); v[3] = (_Float16)(s0.w * s0.w);
        v[4] = (_Float16)(s1.x * s1.x); v[5] = (_Float16)(s1.y * s1.y);
        v[6] = (_Float16)(s1.z * s1.z); v[7] = (_Float16)(s1.w * s1.w);
        am[kk] = a; av[kk] = v;
    }

    f32x4 accm[4], accs[4];
    const f32x4 z = {0.f, 0.f, 0.f, 0.f};
#pragma unroll
    for (int c = 0; c < 4; ++c) { accm[c] = z; accs[c] = z; }

#pragma unroll
    for (int c = 0; c < 4; ++c) {
        accm[c] = __builtin_amdgcn_mfma_f32_16x16x32_f16(am[0], bw[0][0][c], accm[c], 0, 0, 0);
        accm[c] = __builtin_amdgcn_mfma_f32_16x16x32_f16(am[1], bw[0][1][c], accm[c], 0, 0, 0);
        accs[c] = __builtin_amdgcn_mfma_f32_16x16x32_f16(av[0], bw[1][0][c], accs[c], 0, 0, 0);
        accs[c] = __builtin_amdgcn_mfma_f32_16x16x32_f16(av[1], bw[1][1][c], accs[c], 0, 0, 0);
    }

#pragma unroll
    for (int c = 0; c < 4; ++c) {
        const int F = 16 * c + l16;
#pragma unroll
        for (int r = 0; r < 4; ++r) {
            int node = nb + 4 * lg + r;
            float mv = accm[c][r];
            float vv = accs[c][r];
            float mp = __shfl_xor(mv, 1, 64);
            float vp = __shfl_xor(vv, 1, 64);
            if (!(l16 & 1) && node < n) {
                int o = F >> 3, j = (F & 7) >> 1;
                __half2 hm = __floats2half2_rn(mv, mp);
                __half2 hv = __floats2half2_rn(vv, vp);
                pk[(size_t)node * 64 + 8 * o + j]     = *reinterpret_cast<uint*>(&hm);
                pk[(size_t)node * 64 + 8 * o + 4 + j] = *reinterpret_cast<uint*>(&hv);
            }
        }
    }
}

// One wave per node. Wave = 4 edge-groups x 16 lanes; lane16 = chunk id.
__global__ __launch_bounds__(256) void k_aggregate(const uint* __restrict__ pk,
                                                   const int* __restrict__ offsets,
                                                   const uint* __restrict__ erec,
                                                   const float* __restrict__ bm,
                                                   const float* __restrict__ bs,
                                                   float* __restrict__ om,
                                                   float* __restrict__ os, int n) {
    const int lane = threadIdx.x & 63;
    const int wid  = threadIdx.x >> 6;
    const int g    = lane >> 4;      // edge subgroup 0..3
    const int l16  = lane & 15;      // chunk id: t=l16&1, o=l16>>1
    const int t    = l16 & 1;

    const int node = blockIdx.x * 4 + wid;
    if (node >= n) return;
    const int start = offsets[node];
    const int cnt   = offsets[node + 1] - start;

    float accf[8] = {0.f, 0.f, 0.f, 0.f, 0.f, 0.f, 0.f, 0.f};

    for (int base = 0; base < cnt; base += 64) {
        int m = cnt - base;
        if (m > 64) m = 64;
        uint rec = 0;                          // w16=0 -> w=0.0f
        if (lane < m) rec = erec[start + base + lane];
        int mr = (m + 31) & ~31;               // 32 or 64

        for (int j0 = 0; j0 < mr; j0 += 32) {
            uint rr[8];
#pragma unroll
            for (int u = 0; u < 8; ++u)
                rr[u] = (uint)__shfl((int)rec, j0 + 4 * u + g, 64);
            uint4 dd[8];
#pragma unroll
            for (int u = 0; u < 8; ++u)
                dd[u] = *reinterpret_cast<const uint4*>(
                    pk + (size_t)(rr[u] & 0xFFFFu) * 64 + l16 * 4);
            __half2 wh[8];
#pragma unroll
            for (int u = 0; u < 8; ++u) {
                float w = __half2float(__ushort_as_half((ushort)(rr[u] >> 16)));
                float wl = t ? w * w : w;
                __half h = __float2half(wl);
                wh[u] = __halves2half2(h, h);
            }
            __half2 a0 = __halves2half2(__half(0.f), __half(0.f));
            __half2 a1 = a0, a2 = a0, a3 = a0;
#pragma unroll
            for (int u = 0; u < 8; ++u) {
                a0 = __hfma2(*reinterpret_cast<__half2*>(&dd[u].x), wh[u], a0);
                a1 = __hfma2(*reinterpret_cast<__half2*>(&dd[u].y), wh[u], a1);
                a2 = __hfma2(*reinterpret_cast<__half2*>(&dd[u].z), wh[u], a2);
                a3 = __hfma2(*reinterpret_cast<__half2*>(&dd[u].w), wh[u], a3);
            }
            float2 f;
            f = __half22float2(a0); accf[0] += f.x; accf[1] += f.y;
            f = __half22float2(a1); accf[2] += f.x; accf[3] += f.y;
            f = __half22float2(a2); accf[4] += f.x; accf[5] += f.y;
            f = __half22float2(a3); accf[6] += f.x; accf[7] += f.y;
        }
    }

#pragma unroll
    for (int c = 0; c < 8; ++c) {
        accf[c] += __shfl_xor(accf[c], 16, 64);
        accf[c] += __shfl_xor(accf[c], 32, 64);
    }
    // Lane l16 holds accf[c] = aggregated feature 8*(l16>>1)+c of type l16&1.

    if (g == 0) {
        const int f0 = (l16 >> 1) * 8;
        if (!t) {
            float4 b0 = *reinterpret_cast<const float4*>(bm + f0);
            float4 b1 = *reinterpret_cast<const float4*>(bm + f0 + 4);
            float4 r0 = {accf[0] + b0.x, accf[1] + b0.y, accf[2] + b0.z, accf[3] + b0.w};
            float4 r1 = {accf[4] + b1.x, accf[5] + b1.y, accf[6] + b1.z, accf[7] + b1.w};
            *reinterpret_cast<float4*>(om + (size_t)node * 64 + f0)     = r0;
            *reinterpret_cast<float4*>(om + (size_t)node * 64 + f0 + 4) = r1;
        } else {
            float4 b0 = *reinterpret_cast<const float4*>(bs + f0);
            float4 b1 = *reinterpret_cast<const float4*>(bs + f0 + 4);
            float4 r0, r1;
            r0.x = sqrtf(expf(accf[0] + b0.x) + 1e-6f);
            r0.y = sqrtf(expf(accf[1] + b0.y) + 1e-6f);
            r0.z = sqrtf(expf(accf[2] + b0.z) + 1e-6f);
            r0.w = sqrtf(expf(accf[3] + b0.w) + 1e-6f);
            r1.x = sqrtf(expf(accf[4] + b1.x) + 1e-6f);
            r1.y = sqrtf(expf(accf[5] + b1.y) + 1e-6f);
            r1.z = sqrtf(expf(accf[6] + b1.z) + 1e-6f);
            r1.w = sqrtf(expf(accf[7] + b1.w) + 1e-6f);
            *reinterpret_cast<float4*>(os + (size_t)node * 64 + f0)     = r0;
            *reinterpret_cast<float4*>(os + (size_t)node * 64 + f0 + 4) = r1;
        }
    }
}

extern "C" void kernel_launch(void* const* d_in, const int* in_sizes, int n_in,
                              void* d_out, int out_size, void* d_ws, size_t ws_size,
                              hipStream_t stream) {
    const float* mean  = (const float*)d_in[0];
    const float* stdv  = (const float*)d_in[1];
    const int*   ei    = (const int*)d_in[2];
    const float* ew    = (const float*)d_in[3];
    const float* Wm_mu = (const float*)d_in[4];
    const float* Wm_ls = (const float*)d_in[5];
    const float* bm    = (const float*)d_in[6];
    const float* Ws_mu = (const float*)d_in[7];
    const float* Ws_ls = (const float*)d_in[8];
    const float* bs    = (const float*)d_in[9];

    const int n = in_sizes[0] / 64;   // 50000
    const int E = in_sizes[3];        // 1600000
    const int total = n * 64;

    float* om  = (float*)d_out;
    float* os  = om + total;
    float* okl = om + 2 * total;

    char* wsb = (char*)d_ws;
    int* bcnt    = (int*)wsb;                     // 256
    int* bbase   = bcnt + 256;                    // 257 (pad to 288)
    int* bcur    = bbase + 288;                   // 256
    int* offsets = bcur + 256;                    // NPAD + 16
    uchar* dlo   = (uchar*)(offsets + NPAD + 16); // E bytes
    size_t es_off = ((size_t)((char*)(dlo + E) - wsb) + 15) & ~(size_t)15;
    uint* esrcw  = (uint*)(wsb + es_off);         // E (also final erec)
    size_t pk_off = ((size_t)((char*)(esrcw + E) - wsb) + 15) & ~(size_t)15;
    uint* pk     = (uint*)(wsb + pk_off);         // total  (~21 MB overall)

    hipMemsetAsync(bcnt, 0, 256 * sizeof(int), stream);
    k_bucket_hist<<<512, 256, 0, stream>>>(ei, bcnt, E);
    k_bucket_scan_kl<<<2, 256, 0, stream>>>(bcnt, bbase, bcur,
                                            Wm_mu, Wm_ls, Ws_mu, Ws_ls, okl);
    k_bucket_scatter<<<(E + 1023) / 1024, 256, 0, stream>>>(ei, ew, bcur, esrcw, dlo, E);
    k_local_sort<<<NB, 256, 0, stream>>>(bbase, esrcw, dlo, offsets);
    k_transform<<<(n + 63) / 64, 256, 0, stream>>>(mean, stdv, Wm_mu, Ws_mu, pk, n);
    k_aggregate<<<(n + 3) / 4, 256, 0, stream>>>(pk, offsets, esrcw, bm, bs, om, os, n);
}

// Round 9
// 163.162 us; speedup vs baseline: 3.9920x; 1.1055x over previous
//
#include <hip/hip_runtime.h>
#include <hip/hip_fp16.h>
#include <math.h>

// H = 64, N = 50000 nodes, E = 1.6M edges.
// d_out = [ new_mean (N*64) | new_std (N*64) | total_kl (1) ]
//
// Pipeline:
//   1. k_bucket_hist: 196-bucket histogram of dst>>8 (LDS-staged)
//   2. k_bucket_scan_kl: scan bucket counts (block 0) + KL reduction (block 1)
//   3. k_bucket_scatter: group edges by bucket; per-block LDS ranking, one
//      cursor atomic per bucket per block, dense chunked writes
//   4. k_transform (MFMA 16x16x32_f16): h_m = mean@Wm, h_v = (std^2)@Ws,
//      packed fp16 table pk (256 B/node)
//   5. k_sort_agg: one block per (bucket, quarter) = 64 nodes; per-node
//      counting sort of the quarter's records ENTIRELY IN LDS (two filtered
//      passes over the bucket's dlo), then wave-per-node gather-aggregate
//      from the LDS-sorted records; fused bias + sqrt(exp(x)+1e-6).
//
// ws: bcnt[256] | bbase[288] | bcur[256] | dlo uchar[E] | esrcw uint[E]
//     | pk uint[n*64]   (~20 MB)

#define NB   196                 // buckets (dst >> 8), 256 nodes each
#define NSUB 4                   // sub-blocks per bucket (64 nodes each)
#define SCAP 3072                // max records per sub (mean 2048, 22 sigma)

typedef _Float16 half8 __attribute__((ext_vector_type(8)));
typedef float f32x4 __attribute__((ext_vector_type(4)));

__global__ __launch_bounds__(256) void k_bucket_hist(const int* __restrict__ ei,
                                                     int* __restrict__ bcnt, int E) {
    __shared__ int l[NB];
    for (int i = threadIdx.x; i < NB; i += 256) l[i] = 0;
    __syncthreads();
    for (int t = blockIdx.x * 256 + threadIdx.x; t < E; t += gridDim.x * 256)
        atomicAdd(&l[ei[E + t] >> 8], 1);
    __syncthreads();
    for (int i = threadIdx.x; i < NB; i += 256)
        if (l[i]) atomicAdd(&bcnt[i], l[i]);
}

// block 0: exclusive scan of bucket counts -> bbase (+ total at [256]), bcur.
// block 1: KL reduction.
__global__ __launch_bounds__(256) void k_bucket_scan_kl(const int* __restrict__ bcnt,
                                                        int* __restrict__ bbase,
                                                        int* __restrict__ bcur,
                                                        const float* __restrict__ Wm_mu,
                                                        const float* __restrict__ Wm_ls,
                                                        const float* __restrict__ Ws_mu,
                                                        const float* __restrict__ Ws_ls,
                                                        float* __restrict__ okl) {
    if (blockIdx.x == 0) {
        __shared__ int s[256];
        int v = (threadIdx.x < NB) ? bcnt[threadIdx.x] : 0;
        s[threadIdx.x] = v;
        __syncthreads();
        for (int off = 1; off < 256; off <<= 1) {
            int t = 0;
            if (threadIdx.x >= off) t = s[threadIdx.x - off];
            __syncthreads();
            s[threadIdx.x] += t;
            __syncthreads();
        }
        int excl = s[threadIdx.x] - v;
        bbase[threadIdx.x] = excl;
        bcur[threadIdx.x] = excl;
        if (threadIdx.x == 255) bbase[256] = s[255];   // == E
    } else {
        __shared__ float red[256];
        const float C = -2.3025850929940457f - 0.5f;   // log(0.1) - 0.5
        float acc = 0.f;
        for (int i = threadIdx.x; i < 4096; i += 256) {
            {
                float mu = Wm_mu[i], ls = Wm_ls[i];
                float s = expf(ls);
                acc += C - ls + (s * s + mu * mu) * 50.0f;  // 1/(2*0.1^2)
            }
            {
                float mu = Ws_mu[i], ls = Ws_ls[i];
                float s = expf(ls);
                acc += C - ls + (s * s + mu * mu) * 50.0f;
            }
        }
        red[threadIdx.x] = acc;
        __syncthreads();
        for (int s = 128; s > 0; s >>= 1) {
            if (threadIdx.x < s) red[threadIdx.x] += red[threadIdx.x + s];
            __syncthreads();
        }
        if (threadIdx.x == 0) okl[0] = red[0];
    }
}

// Group edges into bucket regions. 1024 edges per block; per-block LDS
// ranking; one cursor atomic per (block, non-empty bucket); chunked writes.
__global__ __launch_bounds__(256) void k_bucket_scatter(const int* __restrict__ ei,
                                                        const float* __restrict__ ew,
                                                        int* __restrict__ bcur,
                                                        uint* __restrict__ esrcw,
                                                        uchar* __restrict__ dlo, int E) {
    __shared__ int lcnt[NB], lpos[NB];
    for (int i = threadIdx.x; i < NB; i += 256) lcnt[i] = 0;
    __syncthreads();
    const int base = blockIdx.x * 1024;
    uint sv[4]; int bb[4], rr[4]; uchar dl4[4]; bool ok[4];
#pragma unroll
    for (int u = 0; u < 4; ++u) {
        int gi = base + u * 256 + threadIdx.x;
        ok[u] = gi < E;
        if (ok[u]) {
            int src = ei[gi];
            int dst = ei[E + gi];
            float w = ew[gi];
            uint w16 = (uint)__half_as_ushort(__float2half(w));
            sv[u] = (w16 << 16) | (uint)src;
            bb[u] = dst >> 8;
            dl4[u] = (uchar)(dst & 255);
            rr[u] = atomicAdd(&lcnt[bb[u]], 1);
        }
    }
    __syncthreads();
    for (int i = threadIdx.x; i < NB; i += 256)
        lpos[i] = lcnt[i] ? atomicAdd(&bcur[i], lcnt[i]) : 0;
    __syncthreads();
#pragma unroll
    for (int u = 0; u < 4; ++u)
        if (ok[u]) {
            int gpos = lpos[bb[u]] + rr[u];
            esrcw[gpos] = sv[u];
            dlo[gpos] = dl4[u];
        }
}

// MFMA transform: h_m = mean@Wm, h_v = (std^2)@Ws, packed fp16 out.
// Block = 4 waves x 16 nodes = 64 nodes. Per wave: 4 col-tiles x 2 K-halves
// x 2 matrices = 16 x mfma_f32_16x16x32_f16.
// A[row=l&15][k=32*kk+8*(l>>4)+j], B[k same][col=l&15] (consistent kappa
// cancels); C/D (HW-verified): col=lane&15, row=(lane>>4)*4+reg.
__global__ __launch_bounds__(256) void k_transform(const float* __restrict__ mean,
                                                   const float* __restrict__ stdv,
                                                   const float* __restrict__ Wm,
                                                   const float* __restrict__ Ws,
                                                   uint* __restrict__ pk, int n) {
    __shared__ float sW[2 * 4096];
    for (int i = threadIdx.x; i < 4096; i += 256) {
        sW[i] = Wm[i];
        sW[4096 + i] = Ws[i];
    }
    __syncthreads();

    const int lane = threadIdx.x & 63;
    const int wid  = threadIdx.x >> 6;
    const int l16  = lane & 15;
    const int lg   = lane >> 4;          // 0..3

    half8 bw[2][2][4];
#pragma unroll
    for (int t = 0; t < 2; ++t)
#pragma unroll
        for (int kk = 0; kk < 2; ++kk)
#pragma unroll
            for (int c = 0; c < 4; ++c) {
                half8 h;
#pragma unroll
                for (int j = 0; j < 8; ++j)
                    h[j] = (_Float16)sW[t * 4096 + (32 * kk + 8 * lg + j) * 64 + 16 * c + l16];
                bw[t][kk][c] = h;
            }

    const int nb = blockIdx.x * 64 + wid * 16;
    int arow = nb + l16;
    if (arow >= n) arow = n - 1;         // clamp; rows >= n never stored

    half8 am[2], av[2];
#pragma unroll
    for (int kk = 0; kk < 2; ++kk) {
        const float* mp = mean + (size_t)arow * 64 + 32 * kk + 8 * lg;
        const float* sp = stdv + (size_t)arow * 64 + 32 * kk + 8 * lg;
        float4 m0 = *(const float4*)mp;
        float4 m1 = *(const float4*)(mp + 4);
        float4 s0 = *(const float4*)sp;
        float4 s1 = *(const float4*)(sp + 4);
        half8 a, v;
        a[0] = (_Float16)m0.x; a[1] = (_Float16)m0.y;
        a[2] = (_Float16)m0.z; a[3] = (_Float16)m0.w;
        a[4] = (_Float16)m1.x; a[5] = (_Float16)m1.y;
        a[6] = (_Float16)m1.z; a[7] = (_Float16)m1.w;
        v[0] = (_Float16)(s0.x * s0.x); v[1] = (_Float16)(s0.y * s0.y);
        v[2] = (_Float16)(s0.z * s0.z); v[3] = (_Float16)(s0.w * s0.w);
        v[4] = (_Float16)(s1.x * s1.x); v[5] = (_Float16)(s1.y * s1.y);
        v[6] = (_Float16)(s1.z * s1.z); v[7] = (_Float16)(s1.w * s1.w);
        am[kk] = a; av[kk] = v;
    }

    f32x4 accm[4], accs[4];
    const f32x4 z = {0.f, 0.f, 0.f, 0.f};
#pragma unroll
    for (int c = 0; c < 4; ++c) { accm[c] = z; accs[c] = z; }

#pragma unroll
    for (int c = 0; c < 4; ++c) {
        accm[c] = __builtin_amdgcn_mfma_f32_16x16x32_f16(am[0], bw[0][0][c], accm[c], 0, 0, 0);
        accm[c] = __builtin_amdgcn_mfma_f32_16x16x32_f16(am[1], bw[0][1][c], accm[c], 0, 0, 0);
        accs[c] = __builtin_amdgcn_mfma_f32_16x16x32_f16(av[0], bw[1][0][c], accs[c], 0, 0, 0);
        accs[c] = __builtin_amdgcn_mfma_f32_16x16x32_f16(av[1], bw[1][1][c], accs[c], 0, 0, 0);
    }

#pragma unroll
    for (int c = 0; c < 4; ++c) {
        const int F = 16 * c + l16;
#pragma unroll
        for (int r = 0; r < 4; ++r) {
            int node = nb + 4 * lg + r;
            float mv = accm[c][r];
            float vv = accs[c][r];
            float mp = __shfl_xor(mv, 1, 64);
            float vp = __shfl_xor(vv, 1, 64);
            if (!(l16 & 1) && node < n) {
                int o = F >> 3, j = (F & 7) >> 1;
                __half2 hm = __floats2half2_rn(mv, mp);
                __half2 hv = __floats2half2_rn(vv, vp);
                pk[(size_t)node * 64 + 8 * o + j]     = *reinterpret_cast<uint*>(&hm);
                pk[(size_t)node * 64 + 8 * o + 4 + j] = *reinterpret_cast<uint*>(&hv);
            }
        }
    }
}

// Fused local sort + aggregate. Block = (bucket b, quarter sub): 64 nodes.
// 512 threads = 8 waves; per-node counting sort in LDS, then wave-per-node
// gather-aggregate (8 nodes per wave) reading records from LDS.
__global__ __launch_bounds__(512) void k_sort_agg(const int* __restrict__ bbase,
                                                  const uint* __restrict__ esrcw,
                                                  const uchar* __restrict__ dlo,
                                                  const uint* __restrict__ pk,
                                                  const float* __restrict__ bm,
                                                  const float* __restrict__ bs,
                                                  float* __restrict__ om,
                                                  float* __restrict__ os, int nv) {
    __shared__ int ncnt[64], sc[64], noff[65], cur[64];
    __shared__ uint sorted[SCAP];
    const int tid = threadIdx.x;
    const int b   = blockIdx.x >> 2;
    const int sub = blockIdx.x & 3;
    const int base = bbase[b];
    const int cnt  = bbase[b + 1] - base;

    if (tid < 64) ncnt[tid] = 0;
    __syncthreads();
    for (int i = tid; i < cnt; i += 512) {
        int d = dlo[base + i];
        if ((d >> 6) == sub) atomicAdd(&ncnt[d & 63], 1);
    }
    __syncthreads();
    if (tid < 64) sc[tid] = ncnt[tid];
    __syncthreads();
    for (int off = 1; off < 64; off <<= 1) {
        int t = 0;
        if (tid < 64 && tid >= off) t = sc[tid - off];
        __syncthreads();
        if (tid < 64) sc[tid] += t;
        __syncthreads();
    }
    if (tid < 64) {
        int excl = sc[tid] - ncnt[tid];
        noff[tid] = excl;
        cur[tid] = excl;
        if (tid == 63) noff[64] = sc[63];
    }
    __syncthreads();
    for (int i = tid; i < cnt; i += 512) {
        int d = dlo[base + i];
        if ((d >> 6) == sub) {
            int pos = atomicAdd(&cur[d & 63], 1);
            if (pos < SCAP) sorted[pos] = esrcw[base + i];
        }
    }
    __syncthreads();

    const int lane = tid & 63;
    const int wave = tid >> 6;       // 0..7
    const int g    = lane >> 4;      // edge subgroup 0..3
    const int l16  = lane & 15;      // chunk id: t=l16&1, o=l16>>1
    const int t    = l16 & 1;

    for (int ln = wave * 8; ln < wave * 8 + 8; ++ln) {
        const int node = b * 256 + sub * 64 + ln;
        const int st = noff[ln];
        const int cn = noff[ln + 1] - st;

        float accf[8] = {0.f, 0.f, 0.f, 0.f, 0.f, 0.f, 0.f, 0.f};

        for (int be = 0; be < cn; be += 64) {
            int m = cn - be;
            if (m > 64) m = 64;
            uint rec = 0;                          // w16=0 -> w=0.0f
            if (lane < m) rec = sorted[st + be + lane];
            int mr = (m + 31) & ~31;               // 32 or 64

            for (int j0 = 0; j0 < mr; j0 += 32) {
                uint rr[8];
#pragma unroll
                for (int u = 0; u < 8; ++u)
                    rr[u] = (uint)__shfl((int)rec, j0 + 4 * u + g, 64);
                uint4 dd[8];
#pragma unroll
                for (int u = 0; u < 8; ++u)
                    dd[u] = *reinterpret_cast<const uint4*>(
                        pk + (size_t)(rr[u] & 0xFFFFu) * 64 + l16 * 4);
                __half2 wh[8];
#pragma unroll
                for (int u = 0; u < 8; ++u) {
                    float w = __half2float(__ushort_as_half((ushort)(rr[u] >> 16)));
                    float wl = t ? w * w : w;
                    __half h = __float2half(wl);
                    wh[u] = __halves2half2(h, h);
                }
                __half2 a0 = __halves2half2(__half(0.f), __half(0.f));
                __half2 a1 = a0, a2 = a0, a3 = a0;
#pragma unroll
                for (int u = 0; u < 8; ++u) {
                    a0 = __hfma2(*reinterpret_cast<__half2*>(&dd[u].x), wh[u], a0);
                    a1 = __hfma2(*reinterpret_cast<__half2*>(&dd[u].y), wh[u], a1);
                    a2 = __hfma2(*reinterpret_cast<__half2*>(&dd[u].z), wh[u], a2);
                    a3 = __hfma2(*reinterpret_cast<__half2*>(&dd[u].w), wh[u], a3);
                }
                float2 f;
                f = __half22float2(a0); accf[0] += f.x; accf[1] += f.y;
                f = __half22float2(a1); accf[2] += f.x; accf[3] += f.y;
                f = __half22float2(a2); accf[4] += f.x; accf[5] += f.y;
                f = __half22float2(a3); accf[6] += f.x; accf[7] += f.y;
            }
        }

#pragma unroll
        for (int c = 0; c < 8; ++c) {
            accf[c] += __shfl_xor(accf[c], 16, 64);
            accf[c] += __shfl_xor(accf[c], 32, 64);
        }
        // Lane l16 holds accf[c] = aggregated feature 8*(l16>>1)+c of type l16&1.

        if (g == 0 && node < nv) {
            const int f0 = (l16 >> 1) * 8;
            if (!t) {
                float4 b0 = *reinterpret_cast<const float4*>(bm + f0);
                float4 b1 = *reinterpret_cast<const float4*>(bm + f0 + 4);
                float4 r0 = {accf[0] + b0.x, accf[1] + b0.y, accf[2] + b0.z, accf[3] + b0.w};
                float4 r1 = {accf[4] + b1.x, accf[5] + b1.y, accf[6] + b1.z, accf[7] + b1.w};
                *reinterpret_cast<float4*>(om + (size_t)node * 64 + f0)     = r0;
                *reinterpret_cast<float4*>(om + (size_t)node * 64 + f0 + 4) = r1;
            } else {
                float4 b0 = *reinterpret_cast<const float4*>(bs + f0);
                float4 b1 = *reinterpret_cast<const float4*>(bs + f0 + 4);
                float4 r0, r1;
                r0.x = sqrtf(expf(accf[0] + b0.x) + 1e-6f);
                r0.y = sqrtf(expf(accf[1] + b0.y) + 1e-6f);
                r0.z = sqrtf(expf(accf[2] + b0.z) + 1e-6f);
                r0.w = sqrtf(expf(accf[3] + b0.w) + 1e-6f);
                r1.x = sqrtf(expf(accf[4] + b1.x) + 1e-6f);
                r1.y = sqrtf(expf(accf[5] + b1.y) + 1e-6f);
                r1.z = sqrtf(expf(accf[6] + b1.z) + 1e-6f);
                r1.w = sqrtf(expf(accf[7] + b1.w) + 1e-6f);
                *reinterpret_cast<float4*>(os + (size_t)node * 64 + f0)     = r0;
                *reinterpret_cast<float4*>(os + (size_t)node * 64 + f0 + 4) = r1;
            }
        }
    }
}

extern "C" void kernel_launch(void* const* d_in, const int* in_sizes, int n_in,
                              void* d_out, int out_size, void* d_ws, size_t ws_size,
                              hipStream_t stream) {
    const float* mean  = (const float*)d_in[0];
    const float* stdv  = (const float*)d_in[1];
    const int*   ei    = (const int*)d_in[2];
    const float* ew    = (const float*)d_in[3];
    const float* Wm_mu = (const float*)d_in[4];
    const float* Wm_ls = (const float*)d_in[5];
    const float* bm    = (const float*)d_in[6];
    const float* Ws_mu = (const float*)d_in[7];
    const float* Ws_ls = (const float*)d_in[8];
    const float* bs    = (const float*)d_in[9];

    const int n = in_sizes[0] / 64;   // 50000
    const int E = in_sizes[3];        // 1600000
    const int total = n * 64;

    float* om  = (float*)d_out;
    float* os  = om + total;
    float* okl = om + 2 * total;

    char* wsb = (char*)d_ws;
    int* bcnt    = (int*)wsb;                     // 256
    int* bbase   = bcnt + 256;                    // 257 (pad to 288)
    int* bcur    = bbase + 288;                   // 256
    uchar* dlo   = (uchar*)(bcur + 256);          // E bytes
    size_t es_off = ((size_t)((char*)(dlo + E) - wsb) + 15) & ~(size_t)15;
    uint* esrcw  = (uint*)(wsb + es_off);         // E
    size_t pk_off = ((size_t)((char*)(esrcw + E) - wsb) + 15) & ~(size_t)15;
    uint* pk     = (uint*)(wsb + pk_off);         // total (~20 MB overall)

    hipMemsetAsync(bcnt, 0, 256 * sizeof(int), stream);
    k_bucket_hist<<<512, 256, 0, stream>>>(ei, bcnt, E);
    k_bucket_scan_kl<<<2, 256, 0, stream>>>(bcnt, bbase, bcur,
                                            Wm_mu, Wm_ls, Ws_mu, Ws_ls, okl);
    k_bucket_scatter<<<(E + 1023) / 1024, 256, 0, stream>>>(ei, ew, bcur, esrcw, dlo, E);
    k_transform<<<(n + 63) / 64, 256, 0, stream>>>(mean, stdv, Wm_mu, Ws_mu, pk, n);
    k_sort_agg<<<NB * NSUB, 512, 0, stream>>>(bbase, esrcw, dlo, pk,
                                              bm, bs, om, os, n);
}